// Round 11
// baseline (135.155 us; speedup 1.0000x reference)
//
#include <hip/hip_runtime.h>
#include <hip/hip_bf16.h>

// out[b,t] = cumsum_t( relu(x @ Wh^T + bh) ) + (x @ Wb + bb)
// B=16384, D=1024, T=512. fp32 in/out; GEMM in bf16 MFMA (fp32 accum).
// R10: R9 structure, BM 64->32 => A-LDS 64KB => 2 blocks/CU x 16 waves
//      = 32 waves/CU (8/SIMD, was 4). Grid 512. The single variable under
//      test is TLP: every pipe idle + occupancy 35% across R1-R9 says
//      latency-bound; 8 waves/SIMD doubles latency cover.

typedef __bf16 bf16x8 __attribute__((ext_vector_type(8)));
typedef float f32x4 __attribute__((ext_vector_type(4)));

#define TDIM 512
#define DDIM 1024
#define BM 32
#define NCH 4            // fill chunks (K=256 each)
#define KS_PER_CH 8      // k-steps (K=32) per chunk
#define BLKE 512         // elements per fragment block (64 lanes x 8)

// ---- kernel 1: Wh fp32 -> bf16 in MFMA-fragment order ----
// dst block (tt,ks): lane l holds Wh[tt*16+(l&15)][ks*32+(l>>4)*8 +0..7]
__global__ __launch_bounds__(256) void prep_wh(const float* __restrict__ src,
                                               __bf16* __restrict__ dst) {
    const int i    = blockIdx.x * 256 + threadIdx.x;   // 0..65535
    const int lane = i & 63;
    const int blk  = i >> 6;          // tt*32 + ks
    const int tt   = blk >> 5;
    const int ks   = blk & 31;
    const int row  = tt * 16 + (lane & 15);
    const int k    = ks * 32 + (lane >> 4) * 8;
    const float4 a = *reinterpret_cast<const float4*>(src + (size_t)row * DDIM + k);
    const float4 b = *reinterpret_cast<const float4*>(src + (size_t)row * DDIM + k + 4);
    bf16x8 o;
    o[0] = (__bf16)a.x; o[1] = (__bf16)a.y; o[2] = (__bf16)a.z; o[3] = (__bf16)a.w;
    o[4] = (__bf16)b.x; o[5] = (__bf16)b.y; o[6] = (__bf16)b.z; o[7] = (__bf16)b.w;
    *reinterpret_cast<bf16x8*>(dst + (size_t)i * 8) = o;
}

// ---- kernel 2: fused GEMM + bias + relu + row-cumsum + base ----
__global__ __launch_bounds__(1024, 8) void survival_kernel(
    const float* __restrict__ x,      // [16384][1024] fp32
    const __bf16* __restrict__ Whb,   // [512*1024] bf16, fragment order
    const float* __restrict__ bh,     // [512]
    const float* __restrict__ Wb,     // [1024]
    const float* __restrict__ bbp,    // [1]
    float* __restrict__ out)          // [16384][512] fp32
{
    // A: [32 rows][128 slots of 16B], slot' = slot ^ (row&7)
    __shared__ __align__(16) char Abf[BM * 2048];   // 64 KB
    __shared__ float baseLds[BM];
    __shared__ float totLds[BM][16];

    const int tid  = threadIdx.x;
    const int lane = tid & 63;
    const int wid  = tid >> 6;      // 0..15: wave owns T-cols [wid*32, wid*32+32)
    const int am   = lane & 15;     // M-col of A frag / T-col of C
    const int kq   = lane >> 4;     // k-quarter
    const int brow = blockIdx.x * BM;
    const float bb0 = bbp[0];

    // --- fill mapping: row ar = tid>>5 (0..31), slot ap = tid&31 ---
    const int ar = tid >> 5;
    const int ap = tid & 31;
    const float* xrow = x + (size_t)(brow + ar) * DDIM;

    float bpart = 0.f;
    f32x4 acc[2][2];
#pragma unroll
    for (int rt = 0; rt < 2; ++rt)
#pragma unroll
        for (int n = 0; n < 2; ++n)
            acc[rt][n] = (f32x4){0.f, 0.f, 0.f, 0.f};

    float4 xs0, xs1;   // in-flight fill regs (named: static, no scratch)

    auto issueFill = [&](int c) {
        const int k0 = c * 256 + ap * 8;
        xs0 = *reinterpret_cast<const float4*>(xrow + k0);
        xs1 = *reinterpret_cast<const float4*>(xrow + k0 + 4);
    };

    auto writeFill = [&](int c) {
        const int k0 = c * 256 + ap * 8;
        const float4 w0 = *reinterpret_cast<const float4*>(Wb + k0);
        const float4 w1 = *reinterpret_cast<const float4*>(Wb + k0 + 4);
        bpart += xs0.x*w0.x + xs0.y*w0.y + xs0.z*w0.z + xs0.w*w0.w
               + xs1.x*w1.x + xs1.y*w1.y + xs1.z*w1.z + xs1.w*w1.w;
        bf16x8 v0;
        v0[0]=(__bf16)xs0.x; v0[1]=(__bf16)xs0.y; v0[2]=(__bf16)xs0.z; v0[3]=(__bf16)xs0.w;
        v0[4]=(__bf16)xs1.x; v0[5]=(__bf16)xs1.y; v0[6]=(__bf16)xs1.z; v0[7]=(__bf16)xs1.w;
        const int s0 = c * 32 + ap;
        *reinterpret_cast<bf16x8*>(&Abf[0] + ar * 2048 + ((s0 ^ (ar & 7)) * 16)) = v0;
    };

    // wave's B base: t-tiles 2*wid, 2*wid+1; block (tt,ks) at elems (tt*32+ks)*BLKE
    const __bf16* bbase = Whb + (size_t)(wid * 2) * 32 * BLKE + (size_t)lane * 8;

    auto computeChunk = [&](int c) {
#pragma unroll
        for (int s = 0; s < KS_PER_CH; ++s) {
            const int ks = c * KS_PER_CH + s;
            const bf16x8 b0 = *reinterpret_cast<const bf16x8*>(bbase + (size_t)ks * BLKE);
            const bf16x8 b1 = *reinterpret_cast<const bf16x8*>(bbase + (size_t)(32 + ks) * BLKE);
            bf16x8 af[2];
#pragma unroll
            for (int rt = 0; rt < 2; ++rt) {
                const int row = rt * 16 + am;
                const int slot = (ks * 4 + kq) ^ (am & 7);
                af[rt] = *reinterpret_cast<const bf16x8*>(&Abf[0] + row * 2048 + slot * 16);
            }
            __builtin_amdgcn_s_setprio(1);
#pragma unroll
            for (int rt = 0; rt < 2; ++rt) {
                acc[rt][0] = __builtin_amdgcn_mfma_f32_16x16x32_bf16(af[rt], b0, acc[rt][0], 0, 0, 0);
                acc[rt][1] = __builtin_amdgcn_mfma_f32_16x16x32_bf16(af[rt], b1, acc[rt][1], 0, 0, 0);
            }
            __builtin_amdgcn_s_setprio(0);
        }
    };

    // --- main: 5 barriers total, no barriers inside compute ---
    issueFill(0);
    writeFill(0);
    __syncthreads();
#pragma unroll
    for (int c = 0; c < NCH; ++c) {
        if (c + 1 < NCH) issueFill(c + 1);    // HBM latency hides under compute
        computeChunk(c);
        if (c + 1 < NCH) { writeFill(c + 1); __syncthreads(); }
    }

    // --- base = x@Wb + bb : reduce 32 partials per row (32-lane halves) ---
    bpart += __shfl_xor(bpart, 1, 32);
    bpart += __shfl_xor(bpart, 2, 32);
    bpart += __shfl_xor(bpart, 4, 32);
    bpart += __shfl_xor(bpart, 8, 32);
    bpart += __shfl_xor(bpart, 16, 32);
    if (ap == 0) baseLds[ar] = bpart + bb0;

    // --- epilogue: bias + relu + in-register inclusive scan over T ---
    // C layout (m89): col(T) = am, row(M) = kq*4 + j within each 16x16 tile
    float bhv[2];
#pragma unroll
    for (int n = 0; n < 2; ++n)
        bhv[n] = bh[wid * 32 + n * 16 + am];

    float carry[2][4];
#pragma unroll
    for (int rt = 0; rt < 2; ++rt)
#pragma unroll
        for (int j = 0; j < 4; ++j) carry[rt][j] = 0.f;

#pragma unroll
    for (int n = 0; n < 2; ++n) {
#pragma unroll
        for (int rt = 0; rt < 2; ++rt) {
#pragma unroll
            for (int j = 0; j < 4; ++j) {
                float v = fmaxf(acc[rt][n][j] + bhv[n], 0.f);
#pragma unroll
                for (int off = 1; off < 16; off <<= 1) {
                    const float u = __shfl_up(v, (unsigned)off, 16);
                    if (am >= off) v += u;
                }
                v += carry[rt][j];
                carry[rt][j] = __shfl(v, 15, 16);
                acc[rt][n][j] = v;
            }
        }
    }

    // per-row 32-col wave totals -> LDS for cross-wave carry
    if (am == 0) {
#pragma unroll
        for (int rt = 0; rt < 2; ++rt)
#pragma unroll
            for (int j = 0; j < 4; ++j)
                totLds[rt * 16 + kq * 4 + j][wid] = carry[rt][j];
    }
    __syncthreads();

#pragma unroll
    for (int rt = 0; rt < 2; ++rt) {
#pragma unroll
        for (int j = 0; j < 4; ++j) {
            const int r = rt * 16 + kq * 4 + j;
            float rc = baseLds[r];
#pragma unroll
            for (int w = 0; w < 15; ++w)
                if (w < wid) rc += totLds[r][w];
            float* orow = out + (size_t)(brow + r) * TDIM + wid * 32 + am;
            orow[0]  = acc[rt][0][j] + rc;
            orow[16] = acc[rt][1][j] + rc;
        }
    }
}

extern "C" void kernel_launch(void* const* d_in, const int* in_sizes, int n_in,
                              void* d_out, int out_size, void* d_ws, size_t ws_size,
                              hipStream_t stream) {
    const float* x  = (const float*)d_in[0];
    const float* Wh = (const float*)d_in[1];
    const float* bh = (const float*)d_in[2];
    const float* Wb = (const float*)d_in[3];
    const float* bb = (const float*)d_in[4];
    float* out = (float*)d_out;
    __bf16* Whb = (__bf16*)d_ws;              // 1 MB scratch, fragment-ordered

    prep_wh<<<256, 256, 0, stream>>>(Wh, Whb);
    survival_kernel<<<512, 1024, 0, stream>>>(x, Whb, bh, Wb, bb, out);
}